// Round 8
// baseline (1518.458 us; speedup 1.0000x reference)
//
#include <hip/hip_runtime.h>
#include <hip/hip_cooperative_groups.h>
#include <stdint.h>
namespace cg = cooperative_groups;

#define RTILE 4096
#define ROUNDS 10

// counters: [1]=M, [2]=group total, [3]=E', [4]=rmax, [7]=const 1 (ON gate),
// [8..8+ROUNDS-1]=per-round unmasked count, [32..35]=pair-sort pass gates,
// [36]=sh (cluster-id bit width), [37]=result-buffer parity (1 => keyB/payB)

// ============================ init ============================
__global__ void k_init_counters(int* counters){
  int t = threadIdx.x;
  counters[t] = 0;
  if (t == 7) counters[7] = 1;
}
__global__ void k_zero_vals(float* vals, int E){
  int i = blockIdx.x*blockDim.x + threadIdx.x;
  if (i < E) vals[i]=0.f;
}

// ============================ key-making ============================
__global__ void k_score_key(const float* score, unsigned* keys, unsigned* pay, int N){
  int i = blockIdx.x*blockDim.x+threadIdx.x;
  if (i<N){
    unsigned b = __float_as_uint(score[i]);
    b ^= ((int)b < 0) ? 0xFFFFFFFFu : 0x80000000u;
    keys[i]=b; pay[i]=(unsigned)i;
  }
}
__global__ void k_rank_build(const unsigned* pay, int* rank, int* pm, int N){
  int p = blockIdx.x*blockDim.x+threadIdx.x;
  if (p<N){ int v = (int)pay[p]; rank[v]=p; pm[v]=p; }
}
__global__ void k_make_colrow(const int* __restrict__ row, const int* __restrict__ col,
                              unsigned* __restrict__ keys, unsigned* __restrict__ pay, int E){
  int e = blockIdx.x*blockDim.x+threadIdx.x;
  if (e<E){ keys[e]=(unsigned)col[e]; pay[e]=(unsigned)row[e]; }
}

// ============================ radix sort: hist (9-bit) ============================
template<typename K, int TILE>
__global__ void k_radix_hist(const K* __restrict__ keys, int n, int shift,
                             unsigned* __restrict__ ghist, int numBlocks, const int* gate){
  if (*gate==0) return;
  __shared__ unsigned h[512];
  int t=threadIdx.x, b=blockIdx.x;
  h[t]=0; h[t+256]=0; __syncthreads();
  int base = b*TILE;
  for (int j=t; j<TILE; j+=256){
    int i = base+j;
    if (i<n){
      unsigned d = (unsigned)((keys[i]>>shift)&(K)511);
      atomicAdd(&h[d],1u);
    }
  }
  __syncthreads();
  ghist[(size_t)t*numBlocks + b] = h[t];
  ghist[(size_t)(t+256)*numBlocks + b] = h[t+256];
}

// ============ radix scatter: wave-parallel ranking, two-phase LDS drain ============
template<typename K, int TILE>
__global__ __launch_bounds__(256)
void k_radix_scatter(const K* __restrict__ keysIn, const unsigned* __restrict__ payIn,
                     K* __restrict__ keysOut, unsigned* __restrict__ payOut,
                     int n, int shift, const unsigned* __restrict__ gbase,
                     int numBlocks, const int* gate){
  if (*gate==0) return;
  constexpr int G = TILE/256;
  constexpr int SEG = TILE/4;
  __shared__ __align__(16) char smem[(size_t)TILE*sizeof(K)];
  K* skey = (K*)smem;
  unsigned* spay = (unsigned*)smem;  // aliased, used after keys drained
  __shared__ unsigned whist[4][512];
  __shared__ unsigned lbase[512];
  __shared__ unsigned ss[256];
  int t=threadIdx.x, b=blockIdx.x;
  int lane = t&63, wave = t>>6;
  int base = b*TILE;
  int tilecnt = min(TILE, n-base);
  int segBase = base + wave*SEG;

  for (int j=lane; j<512; j+=64) whist[wave][j]=0;
  K keys[G]; unsigned pays[G];
  for (int g=0; g<G; ++g){
    int i = segBase + g*64 + lane;
    bool valid = i<n;
    keys[g] = valid ? keysIn[i] : (K)0;
    pays[g] = valid ? payIn[i] : 0u;
    if (valid){
      unsigned d = (unsigned)((keys[g]>>shift)&(K)511);
      atomicAdd(&whist[wave][d],1u);
    }
  }
  __syncthreads();

  unsigned h0[4], h1[4], u0=0, u1=0;
  #pragma unroll
  for (int w=0;w<4;++w){ h0[w]=whist[w][2*t];   u0+=h0[w];
                         h1[w]=whist[w][2*t+1]; u1+=h1[w]; }
  ss[t]=u0+u1; __syncthreads();
  for (int off=1; off<256; off<<=1){
    unsigned x=(t>=off)?ss[t-off]:0u; __syncthreads();
    ss[t]+=x; __syncthreads();
  }
  unsigned excl = t? ss[t-1]:0u;
  lbase[2*t]=excl; lbase[2*t+1]=excl+u0;
  unsigned c0=excl, c1=excl+u0;
  #pragma unroll
  for (int w=0;w<4;++w){ whist[w][2*t]=c0;   c0+=h0[w];
                         whist[w][2*t+1]=c1; c1+=h1[w]; }
  __syncthreads();

  unsigned offs[G];
  for (int g=0; g<G; ++g){
    int i = segBase + g*64 + lane;
    bool valid = i<n;
    unsigned d = (unsigned)((keys[g]>>shift)&(K)511);
    unsigned long long m = __ballot(valid);
    #pragma unroll
    for (int bit=0; bit<9; ++bit){
      unsigned long long bb = __ballot((d>>bit)&1u);
      m &= ((d>>bit)&1u) ? bb : ~bb;
    }
    if (valid){
      int lr = __popcll(m & ((1ull<<lane)-1ull));
      int leader = __ffsll((unsigned long long)m)-1;
      unsigned old=0;
      if (lr==0) old = atomicAdd(&whist[wave][d], (unsigned)__popcll(m));
      old = __shfl(old, leader);
      unsigned o = old + (unsigned)lr;
      skey[o]=keys[g]; offs[g]=o;
    }
  }
  __syncthreads();

  unsigned gpos_[G];
  for (int c=0;c<G;++c){
    int j=c*256+t;
    if (j<tilecnt){
      K k=skey[j];
      unsigned d=(unsigned)((k>>shift)&(K)511);
      unsigned gp = gbase[(size_t)d*numBlocks + b] + ((unsigned)j - lbase[d]);
      keysOut[gp]=k; gpos_[c]=gp;
    }
  }
  __syncthreads();
  for (int g=0; g<G; ++g){
    int i = segBase + g*64 + lane;
    if (i<n) spay[offs[g]]=pays[g];
  }
  __syncthreads();
  for (int c=0;c<G;++c){
    int j=c*256+t;
    if (j<tilecnt) payOut[gpos_[c]] = spay[j];
  }
}

// ============================ scans (templated) ============================
template<typename T>
__global__ void k_scan_single(T* data, int n, T* total, const int* gate){
  if (*gate==0) return;
  __shared__ T sh[1024];
  __shared__ T carry;
  int t=threadIdx.x;
  if (t==0) carry=(T)0;
  __syncthreads();
  for (int base=0; base<n; base+=4096){
    T v[4]; T s=(T)0;
    int i0 = base + t*4;
    #pragma unroll
    for (int j=0;j<4;j++){ int i=i0+j; v[j] = (i<n)?data[i]:(T)0; s+=v[j]; }
    sh[t]=s; __syncthreads();
    for (int off=1; off<1024; off<<=1){
      T x = (t>=off)? sh[t-off]:(T)0; __syncthreads();
      sh[t]+=x; __syncthreads();
    }
    T excl = (t?sh[t-1]:(T)0) + carry;
    #pragma unroll
    for (int j=0;j<4;j++){ int i=i0+j; if(i<n){ T o=v[j]; data[i]=excl; excl+=o; } }
    T tot = sh[1023];
    __syncthreads();
    if (t==0) carry += tot;
    __syncthreads();
  }
  if (total && t==0) *total = carry;
}
template<typename T>
__global__ void k_scan_partials(const T* __restrict__ in, T* __restrict__ bsums,
                                int n, const int* gate){
  if (*gate==0) return;
  __shared__ T sh[256];
  int b=blockIdx.x, t=threadIdx.x;
  long base = (long)b*RTILE + (long)t*16;
  T s=(T)0;
  #pragma unroll
  for (int j=0;j<16;j++){ long i=base+j; if(i<n) s+=in[i]; }
  sh[t]=s; __syncthreads();
  for (int off=128; off>0; off>>=1){ if(t<off) sh[t]+=sh[t+off]; __syncthreads(); }
  if (t==0) bsums[b]=sh[0];
}
template<typename T>
__global__ void k_scan_final(const T* __restrict__ in, T* __restrict__ out,
                             const T* __restrict__ bsums, int n, const int* gate){
  if (*gate==0) return;
  __shared__ T sh[256];
  int b=blockIdx.x, t=threadIdx.x;
  long base = (long)b*RTILE + (long)t*16;
  T v[16]; T s=(T)0;
  #pragma unroll
  for (int j=0;j<16;j++){ long i=base+j; v[j]=(i<n)?in[i]:(T)0; s+=v[j]; }
  sh[t]=s; __syncthreads();
  for (int off=1; off<256; off<<=1){
    T x=(t>=off)?sh[t-off]:(T)0; __syncthreads(); sh[t]+=x; __syncthreads();
  }
  T run=(t?sh[t-1]:(T)0)+bsums[b];
  #pragma unroll
  for (int j=0;j<16;j++){ long i=base+j; if(i<n){ T o=v[j]; out[i]=run; run+=o; } }
}

// ============================ CSR offsets from sorted cols ============================
__global__ void k_build_off(const unsigned* __restrict__ scol, int* __restrict__ off, int E, int N){
  int i = blockIdx.x*blockDim.x+threadIdx.x;
  if (i>=E) return;
  int c = (int)scol[i];
  int p = (i==0) ? -1 : (int)scol[i-1];
  for (int v=p+1; v<=c; ++v) off[v]=i;
  if (i==E-1){ for (int v=c+1; v<=N; ++v) off[v]=E; }
}

// ============== fused MIS + cluster-gather: ONE cooperative kernel ==============
// pm[v] = mask?N:rank. 4 lanes per node; grid.sync between phases; uniform
// break on convergence. Tail: pm:=mis?rank:N, cidx:=mis, mnArr = min over
// closed neighborhood.
__global__ __launch_bounds__(256,4)
void k_mis_coop(const int* __restrict__ off, const int* __restrict__ nbr,
                const int* __restrict__ rank, int* __restrict__ pm,
                int* __restrict__ mis, int* __restrict__ maskA,
                unsigned* __restrict__ cidx, int* __restrict__ mnArr,
                int N, int* __restrict__ cnt){
  cg::grid_group grid = cg::this_grid();
  int gT = gridDim.x*blockDim.x;
  int tid0 = blockIdx.x*blockDim.x + threadIdx.x;
  __shared__ int s_go;
  for (int r=0; r<ROUNDS; ++r){
    // phase 1: new MIS members; maskA = mask_old | new_mis
    for (int t4 = tid0; t4 < 4*N; t4 += gT){
      int v = t4>>2, q = t4&3;
      int p = pm[v];
      if (p == N){ if (q==0) maskA[v]=1; continue; }
      int m = p;
      int s=off[v], e=off[v+1];
      for (int j=s+q; j<e; j+=4) m = min(m, pm[nbr[j]]);
      m = min(m, __shfl_xor(m,1));
      m = min(m, __shfl_xor(m,2));
      if (q==0){
        int nm = (m==p);                 // rank unique => local min <=> new MIS
        if (r==0) mis[v]=nm; else if (nm) mis[v]=1;
        maskA[v]=nm;
      }
    }
    grid.sync();
    // phase 2: mask |= neighbor(maskA); pm; count unmasked
    for (int t4 = tid0; t4 < 4*N; t4 += gT){
      int v = t4>>2, q = t4&3;
      int mk = maskA[v];
      if (!mk){
        int s=off[v], e=off[v+1];
        for (int j=s+q; j<e && !mk; j+=4) mk |= maskA[nbr[j]];
      }
      mk |= __shfl_xor(mk,1);
      mk |= __shfl_xor(mk,2);
      if (q==0){
        if (mk) pm[v]=N;
        else atomicAdd(cnt+r, 1);        // compiler wave-coalesces
      }
    }
    grid.sync();
    if (threadIdx.x==0)
      s_go = __hip_atomic_load(cnt+r, __ATOMIC_RELAXED, __HIP_MEMORY_SCOPE_AGENT);
    __syncthreads();
    if (s_go == 0) break;                // uniform across grid
  }
  // tail A: pm := mis?rank:N ; cidx := mis
  for (int v = tid0; v < N; v += gT){
    int mi = mis[v];
    pm[v] = mi ? rank[v] : N;
    cidx[v] = (unsigned)mi;
  }
  grid.sync();
  // tail B: mnArr = min over closed neighborhood of pm
  for (int t4 = tid0; t4 < 4*N; t4 += gT){
    int v = t4>>2, q = t4&3;
    int m = pm[v];
    int s=off[v], e=off[v+1];
    for (int j=s+q; j<e; j+=4) m = min(m, pm[nbr[j]]);
    m = min(m, __shfl_xor(m,1));
    m = min(m, __shfl_xor(m,2));
    if (q==0) mnArr[v]=m;
  }
}

// ============================ clustering epilogue ============================
__global__ void k_cl_map(const int* rank, const int* mis, const unsigned* cidx,
                         int* map, int* rmax, int N){
  int v = blockIdx.x*blockDim.x+threadIdx.x;
  if (v<N && mis[v]){ map[rank[v]] = (int)cidx[v]; atomicMax(rmax, rank[v]); }
}
__global__ void k_cl_cluster(const int* mn, const int* map, const int* rmax, int* cluster, int N){
  int v = blockIdx.x*blockDim.x+threadIdx.x;
  if (v<N){
    int mr = mn[v];
    if (mr >= N) mr = *rmax;             // JAX OOB-gather clamp semantics
    cluster[v] = map[mr];
  }
}
__global__ void k_gather_x(const float4* __restrict__ x, float4* __restrict__ out,
                           const int* __restrict__ mis, const unsigned* __restrict__ cidx,
                           int N, int D4){
  int t = blockIdx.x*blockDim.x+threadIdx.x;
  int v = t / D4, q = t - v*D4;
  if (v<N && mis[v]) out[(size_t)cidx[v]*D4 + q] = x[(size_t)v*D4 + q];
}

// ============================ coarsened-edge aggregation (u32 keys) ============================
// Assumes M <= 65536 so (a<<sh)|b fits 32 bits (M ~ 6.5k for this input).
__global__ void k_set_gates(int* counters){
  int M = counters[1];
  int sh = (M<=1) ? 1 : (32-__clz((unsigned)(M-1)));
  int kb = 2*sh;
  int npass = 1 + (9<kb) + (18<kb) + (27<kb);
  counters[36] = sh;
  counters[32] = 1;
  counters[33] = (9  < kb);
  counters[34] = (18 < kb);
  counters[35] = (27 < kb);
  counters[37] = npass & 1;              // 1 => final data in keyB/payB
}
__global__ void k_pair_key(const int* __restrict__ row, const int* __restrict__ col,
                           const int* __restrict__ cluster, const float* __restrict__ attr,
                           unsigned* __restrict__ keys, unsigned* __restrict__ pay,
                           const int* __restrict__ counters, int E){
  int e = blockIdx.x*blockDim.x+threadIdx.x;
  if (e<E){
    int sh = counters[36];
    unsigned a = (unsigned)cluster[row[e]], b=(unsigned)cluster[col[e]];
    keys[e] = (a<<sh) | b;
    pay[e] = __float_as_uint(attr[e]);
  }
}
// fused flags packed into one u64: low32=head, high32=keep
__global__ void k_flags(const unsigned* __restrict__ keyA,
                        const unsigned* __restrict__ keyB,
                        unsigned long long* __restrict__ fcomb,
                        const int* __restrict__ counters, int E){
  const unsigned* keys = counters[37] ? keyB : keyA;
  int i = blockIdx.x*blockDim.x+threadIdx.x;
  if (i<E){
    int sh = counters[36];
    unsigned k = keys[i];
    unsigned head = (i==0) || (k != keys[i-1]);
    unsigned a=k>>sh, b=k&((1u<<sh)-1u);
    unsigned keep = (head && a!=b) ? 1u : 0u;
    fcomb[i] = ((unsigned long long)keep<<32) | head;
  }
}
__global__ void k_acc_seg(const unsigned* __restrict__ keyA, const unsigned* __restrict__ keyB,
                          const unsigned* __restrict__ payA, const unsigned* __restrict__ payB,
                          const unsigned long long* __restrict__ fcomb,
                          float* __restrict__ vals, const int* __restrict__ counters, int E){
  const unsigned* keys = counters[37] ? keyB : keyA;
  const unsigned* pay = counters[37] ? payB : payA;
  int i = blockIdx.x*blockDim.x+threadIdx.x;
  int lane = threadIdx.x & 63;
  bool valid = i < E;
  unsigned k = valid ? keys[i] : ~0u;
  float v = valid ? __uint_as_float(pay[i]) : 0.f;
  #pragma unroll
  for (int off=1; off<64; off<<=1){
    float o = __shfl_up(v, off);
    unsigned ko = __shfl_up(k, off);
    if (lane >= off && ko == k) v += o;
  }
  if (valid){
    unsigned knext = (i+1<E) ? keys[i+1] : ~0u;
    if (lane==63 || k != knext){
      unsigned head = (i==0) || (keys[i-1] != k);
      unsigned e1 = (unsigned)fcomb[i];
      atomicAdd(&vals[e1 + head - 1u], v);
    }
  }
}
__global__ void k_write_edges(const unsigned* __restrict__ keyA, const unsigned* __restrict__ keyB,
                              const unsigned long long* __restrict__ fcomb,
                              const float* __restrict__ vals, float* __restrict__ out,
                              const int* __restrict__ counters, int E, int D){
  const unsigned* keys = counters[37] ? keyB : keyA;
  int i = blockIdx.x*blockDim.x+threadIdx.x;
  if (i<E){
    int sh = counters[36];
    int head=(i==0)||(keys[i]!=keys[i-1]);
    unsigned a=keys[i]>>sh, b=keys[i]&((1u<<sh)-1u);
    if (head && a!=b){
      unsigned long long sc = fcomb[i];
      unsigned opos = (unsigned)(sc>>32);
      int M = counters[1], Ep = counters[3];
      size_t off = (size_t)M*D;
      out[off + opos] = (float)a;
      out[off + (size_t)Ep + opos] = (float)b;
      out[off + 2*(size_t)Ep + opos] = vals[(unsigned)sc];
    }
  }
}
__global__ void k_write_nodes(const int* __restrict__ cluster, const int* __restrict__ mis,
                              const float* __restrict__ score, float* __restrict__ out,
                              const int* __restrict__ counters, int N, int D){
  int v = blockIdx.x*blockDim.x+threadIdx.x;
  if (v<N){
    int M=counters[1], Ep=counters[3];
    size_t off = (size_t)M*D + 3*(size_t)Ep;
    out[off + v] = (float)cluster[v];
    out[off + (size_t)N + v] = mis[v] ? 1.f : 0.f;
    out[off + 2*(size_t)N + v] = score[v];
  }
}

// ============================ host helpers ============================
template<typename T>
static void big_scan_t(T* data, int n, T* total, const int* gate, void* bsums_raw, hipStream_t stream){
  int B = (n + RTILE-1)/RTILE;
  T* bsums = (T*)bsums_raw;
  k_scan_partials<T><<<B,256,0,stream>>>(data,bsums,n,gate);
  k_scan_single<T><<<1,1024,0,stream>>>(bsums,B,total,gate);
  k_scan_final<T><<<B,256,0,stream>>>(data,data,bsums,n,gate);
}

// ============================ host ============================
extern "C" void kernel_launch(void* const* d_in, const int* in_sizes, int n_in,
                              void* d_out, int out_size, void* d_ws, size_t ws_size,
                              hipStream_t stream){
  const float* x     = (const float*)d_in[0];
  const int*   ei    = (const int*)d_in[1];
  const float* attr  = (const float*)d_in[2];
  const float* score = (const float*)d_in[3];
  int N = in_sizes[3];
  int E = in_sizes[2];
  int D = in_sizes[0]/N;
  const int* row = ei;
  const int* col = ei + E;
  float* out = (float*)d_out;

  char* p = (char*)d_ws;
  auto alloc = [&](size_t bytes)->char*{ char* r=p; p += ((bytes+255)/256)*256; return r; };
  unsigned* keyA  = (unsigned*)alloc((size_t)E*4);
  unsigned* keyB  = (unsigned*)alloc((size_t)E*4);
  unsigned* payA  = (unsigned*)alloc((size_t)E*4);
  unsigned* payB  = (unsigned*)alloc((size_t)E*4);
  unsigned* scanA = (unsigned*)alloc((size_t)E*4);
  unsigned long long* fcomb = (unsigned long long*)alloc((size_t)E*8);
  float*    vals  = (float*)alloc((size_t)E*4);
  int* csr_row = (int*)alloc((size_t)E*4);
  unsigned* off= (unsigned*)alloc((size_t)(N+1)*4);
  int* rank   = (int*)alloc((size_t)N*4);
  int* pm     = (int*)alloc((size_t)N*4);
  int* mis    = (int*)alloc((size_t)N*4);
  int* maskA  = (int*)alloc((size_t)N*4);
  int* mnArr  = (int*)alloc((size_t)N*4);
  int* map    = (int*)alloc((size_t)N*4);
  unsigned* cidx = (unsigned*)alloc((size_t)N*4);
  int* cluster= (int*)alloc((size_t)N*4);
  int* counters=(int*)alloc(256*4);
  int Be = (E + RTILE-1)/RTILE;
  int Bn1k = (N + 1023)/1024;
  unsigned* ghist = (unsigned*)alloc((size_t)512*Be*4);
  void* bsums = (void*)alloc(4096*8);

  int nbN = (N+255)/256, nbE = (E+255)/256;
  const int* ON = counters+7;

  k_init_counters<<<1,256,0,stream>>>(counters);
  k_zero_vals<<<nbE,256,0,stream>>>(vals,E);

  // ---- CSR: sort (col,row) by col with 2 LDS-staged radix passes, then offsets ----
  k_make_colrow<<<nbE,256,0,stream>>>(row,col,keyA,payA,E);
  k_radix_hist<unsigned,RTILE><<<Be,256,0,stream>>>(keyA,E,0,ghist,Be,ON);
  big_scan_t<unsigned>(ghist,512*Be,nullptr,ON,bsums,stream);
  k_radix_scatter<unsigned,RTILE><<<Be,256,0,stream>>>(keyA,payA,keyB,payB,E,0,ghist,Be,ON);
  k_radix_hist<unsigned,RTILE><<<Be,256,0,stream>>>(keyB,E,9,ghist,Be,ON);
  big_scan_t<unsigned>(ghist,512*Be,nullptr,ON,bsums,stream);
  k_radix_scatter<unsigned,RTILE><<<Be,256,0,stream>>>(keyB,payB,scanA,(unsigned*)csr_row,E,9,ghist,Be,ON);
  k_build_off<<<nbE,256,0,stream>>>(scanA,(int*)off,E,N);

  // ---- rank = stable argsort(argsort(score)), 4 passes of 9 bits, TILE=1024 ----
  k_score_key<<<nbN,256,0,stream>>>(score,keyA,payA,N);
  {
    unsigned *ki=keyA,*ko=keyB,*pi=payA,*po=payB;
    for (int pass=0; pass<4; ++pass){
      int shift = pass*9;
      k_radix_hist<unsigned,1024><<<Bn1k,256,0,stream>>>(ki,N,shift,ghist,Bn1k,ON);
      big_scan_t<unsigned>(ghist,512*Bn1k,nullptr,ON,bsums,stream);
      k_radix_scatter<unsigned,1024><<<Bn1k,256,0,stream>>>(ki,pi,ko,po,N,shift,ghist,Bn1k,ON);
      unsigned* tk=ki; ki=ko; ko=tk; unsigned* tp=pi; pi=po; po=tp;
    }
    k_rank_build<<<nbN,256,0,stream>>>(pi, rank, pm, N);
  }

  // ---- MIS + cluster gather: one cooperative kernel ----
  {
    const int* off_i = (const int*)off;
    const int* nbr_i = (const int*)csr_row;
    const int* rank_i = (const int*)rank;
    int* cntp = counters + 8;
    void* cargs[] = {(void*)&off_i, (void*)&nbr_i, (void*)&rank_i, (void*)&pm,
                     (void*)&mis, (void*)&maskA, (void*)&cidx, (void*)&mnArr,
                     (void*)&N, (void*)&cntp};
    hipLaunchCooperativeKernel((const void*)k_mis_coop, dim3(1024), dim3(256),
                               cargs, 0, stream);
  }

  // ---- clustering epilogue ----
  big_scan_t<unsigned>(cidx,N,(unsigned*)(counters+1),ON,bsums,stream);   // M = #MIS
  k_cl_map<<<nbN,256,0,stream>>>(rank,mis,cidx,map,counters+4,N);
  k_cl_cluster<<<nbN,256,0,stream>>>(mnArr,map,counters+4,cluster,N);
  k_gather_x<<<(N*(D/4)+255)/256,256,0,stream>>>((const float4*)x,(float4*)out,mis,cidx,N,D/4);

  // ---- coarsened edges: u32 pair sort, gated passes, parity select ----
  k_set_gates<<<1,1,0,stream>>>(counters);
  k_pair_key<<<nbE,256,0,stream>>>(row,col,cluster,attr,keyA,payA,counters,E);
  {
    unsigned *ki=keyA,*ko=keyB,*pi=payA,*po=payB;
    for (int pass=0; pass<4; ++pass){
      int shift = pass*9;
      const int* g = counters + 32 + pass;
      k_radix_hist<unsigned,RTILE><<<Be,256,0,stream>>>(ki,E,shift,ghist,Be,g);
      big_scan_t<unsigned>(ghist,512*Be,nullptr,g,bsums,stream);
      k_radix_scatter<unsigned,RTILE><<<Be,256,0,stream>>>(ki,pi,ko,po,E,shift,ghist,Be,g);
      unsigned* tk=ki; ki=ko; ko=tk; unsigned* tp=pi; pi=po; po=tp;
    }
    k_flags<<<nbE,256,0,stream>>>(keyA,keyB,fcomb,counters,E);
    big_scan_t<unsigned long long>(fcomb,E,(unsigned long long*)(counters+2),ON,bsums,stream);
    k_acc_seg<<<nbE,256,0,stream>>>(keyA,keyB,payA,payB,fcomb,vals,counters,E);
    k_write_edges<<<nbE,256,0,stream>>>(keyA,keyB,fcomb,vals,out,counters,E,D);
  }
  k_write_nodes<<<nbN,256,0,stream>>>(cluster,mis,score,out,counters,N,D);
}